// Round 7
// baseline (264.600 us; speedup 1.0000x reference)
//
#include <hip/hip_runtime.h>
#include <hip/hip_bf16.h>

typedef short bf16x8 __attribute__((ext_vector_type(8)));
typedef float f32x4 __attribute__((ext_vector_type(4)));
typedef unsigned short u16;
typedef u16 u16x4 __attribute__((ext_vector_type(4)));
typedef u16 u16x8 __attribute__((ext_vector_type(8)));

#define MFMA16(a, b, c) __builtin_amdgcn_mfma_f32_16x16x32_bf16(a, b, c, 0, 0, 0)

// B=2, T=1024, C=1024, H=16, HD=64.
// Inputs fp32; outputs fp32: y [2M], a [32M].
// d_ws (u16 elems): q[2M] k[2M] vt[2M] ao[2M] Qb[2M] Kb[2M] Vb[2M]
//                   Wqb[1M] Wkb[1M] Wvb[1M] Wpb[1M]  = 18M u16 = 36 MB.

__device__ __forceinline__ u16 f2bf(float f) {
    unsigned u = __builtin_bit_cast(unsigned, f);
    unsigned r = (u + 0x7FFFu + ((u >> 16) & 1u)) >> 16;
    return (u16)r;
}

__device__ __forceinline__ float bf2f(u16 v) {
    return __builtin_bit_cast(float, ((unsigned)v) << 16);
}

// ---------------------------------------------------------------------------
// cvt_bf16 prepass: fp32 -> bf16 (RNE) for all GEMM operands, once.
// grid (1024, 7); z: 0=Q 1=K 2=V 3=Wq 4=Wk 5=Wv 6=Wp.
// ---------------------------------------------------------------------------
__global__ __launch_bounds__(256) void cvt_bf16(
    const float* __restrict__ Q, const float* __restrict__ K, const float* __restrict__ V,
    const float* __restrict__ Wq, const float* __restrict__ Wk, const float* __restrict__ Wv,
    const float* __restrict__ Wp,
    u16* __restrict__ Qb, u16* __restrict__ Kb, u16* __restrict__ Vb,
    u16* __restrict__ Wqb, u16* __restrict__ Wkb, u16* __restrict__ Wvb,
    u16* __restrict__ Wpb) {
    const int z = blockIdx.y;
    const float* src;
    u16* dst;
    int n;
    switch (z) {
        case 0: src = Q;  dst = Qb;  n = 1 << 21; break;
        case 1: src = K;  dst = Kb;  n = 1 << 21; break;
        case 2: src = V;  dst = Vb;  n = 1 << 21; break;
        case 3: src = Wq; dst = Wqb; n = 1 << 20; break;
        case 4: src = Wk; dst = Wkb; n = 1 << 20; break;
        case 5: src = Wv; dst = Wvb; n = 1 << 20; break;
        default: src = Wp; dst = Wpb; n = 1 << 20; break;
    }
    const int i = (blockIdx.x * 256 + threadIdx.x) * 8;
    if (i >= n) return;
    float4 f0 = *(const float4*)(src + i);
    float4 f1 = *(const float4*)(src + i + 4);
    u16x8 t;
    t[0] = f2bf(f0.x); t[1] = f2bf(f0.y); t[2] = f2bf(f0.z); t[3] = f2bf(f0.w);
    t[4] = f2bf(f1.x); t[5] = f2bf(f1.y); t[6] = f2bf(f1.z); t[7] = f2bf(f1.w);
    *(u16x8*)(dst + i) = t;
}

// ---------------------------------------------------------------------------
// m97-style bt-GEMM: out = A(Mx1024) @ W(1024x1024)^T + bias.
// Linear LDS [row][64], staged via global_load_lds width=16 (no VALU staging).
// BM x BN tile, BK=64, 4 waves (2x2). proj_qkv: 128x128; proj_out: 64x64.
// mode 0: [b,h,t,d]; mode 1: [b,h,d,t]; mode 2: row-major (fp32 y).
// ---------------------------------------------------------------------------
template <int BM, int BN, bool OF32>
__device__ inline void gemm_body(const u16* __restrict__ A,
                                 const u16* __restrict__ W,
                                 const float* __restrict__ bias,
                                 void* __restrict__ outp, int mode) {
    __shared__ u16 As[BM * 64];   // [row][64] linear
    __shared__ u16 Bs[BN * 64];   // [row][64] linear

    const int tid = threadIdx.x;
    const int wave = tid >> 6, lane = tid & 63;
    const int quad = lane >> 4, l16 = lane & 15;
    constexpr int WM = BM / 2;    // wave tile rows
    constexpr int WN = BN / 2;    // wave tile cols
    constexpr int MI = WM / 16;   // m-frags per wave
    constexpr int NI = WN / 16;   // n-frags per wave
    const int wm = (wave >> 1) * WM;
    const int wn = (wave & 1) * WN;
    const int m0 = blockIdx.y * BM;
    const int n0 = blockIdx.x * BN;

    f32x4 acc[MI][NI] = {};

    const int lrow = lane >> 3;
    const int lseg = lane & 7;
    const u16* Ag = A + (size_t)(m0 + wave * 8 + lrow) * 1024 + lseg * 8;
    const u16* Wg = W + (size_t)(n0 + wave * 8 + lrow) * 1024 + lseg * 8;
    u16* AsBase = As + wave * 8 * 64;
    u16* BsBase = Bs + wave * 8 * 64;

    for (int kt = 0; kt < 16; ++kt) {
        const int k0 = kt * 64;
        __syncthreads();
#pragma unroll
        for (int rr = 0; rr < BM / 32; ++rr)
            __builtin_amdgcn_global_load_lds(
                (const __attribute__((address_space(1))) void*)(Ag + (size_t)rr * 32 * 1024 + k0),
                (__attribute__((address_space(3))) void*)(AsBase + rr * 32 * 64), 16, 0, 0);
#pragma unroll
        for (int rr = 0; rr < BN / 32; ++rr)
            __builtin_amdgcn_global_load_lds(
                (const __attribute__((address_space(1))) void*)(Wg + (size_t)rr * 32 * 1024 + k0),
                (__attribute__((address_space(3))) void*)(BsBase + rr * 32 * 64), 16, 0, 0);
        __syncthreads();
#pragma unroll
        for (int ks = 0; ks < 2; ++ks) {
            bf16x8 af[MI], bfr[NI];
#pragma unroll
            for (int mi = 0; mi < MI; ++mi)
                af[mi] = *(const bf16x8*)(As + (wm + mi * 16 + l16) * 64 + ks * 32 + quad * 8);
#pragma unroll
            for (int ni = 0; ni < NI; ++ni)
                bfr[ni] = *(const bf16x8*)(Bs + (wn + ni * 16 + l16) * 64 + ks * 32 + quad * 8);
#pragma unroll
            for (int mi = 0; mi < MI; ++mi)
#pragma unroll
                for (int ni = 0; ni < NI; ++ni)
                    acc[mi][ni] = MFMA16(af[mi], bfr[ni], acc[mi][ni]);
        }
    }

#pragma unroll
    for (int ni = 0; ni < NI; ++ni) {
        const int n = n0 + wn + ni * 16 + l16;
        const float bv = bias[n];
#pragma unroll
        for (int mi = 0; mi < MI; ++mi) {
#pragma unroll
            for (int r = 0; r < 4; ++r) {
                const int m = m0 + wm + mi * 16 + quad * 4 + r;
                const float val = acc[mi][ni][r] + bv;
                size_t idx;
                if (mode == 0) {
                    int b = m >> 10, t = m & 1023, h = n >> 6, d = n & 63;
                    idx = ((size_t)((b * 16 + h) * 1024 + t)) * 64 + d;
                } else if (mode == 1) {
                    int b = m >> 10, t = m & 1023, h = n >> 6, d = n & 63;
                    idx = ((size_t)((b * 16 + h) * 64 + d)) * 1024 + t;
                } else {
                    idx = (size_t)m * 1024 + n;
                }
                if (OF32) ((float*)outp)[idx] = val;
                else      ((u16*)outp)[idx] = f2bf(val);
            }
        }
    }
}

__global__ __launch_bounds__(256) void proj_qkv(
    const u16* __restrict__ Qb, const u16* __restrict__ Kb, const u16* __restrict__ Vb,
    const u16* __restrict__ Wqb, const u16* __restrict__ Wkb, const u16* __restrict__ Wvb,
    const float* __restrict__ bq, const float* __restrict__ bk, const float* __restrict__ bv,
    u16* __restrict__ q_ws, u16* __restrict__ k_ws, u16* __restrict__ vt_ws) {
    const int z = blockIdx.z;
    const u16* A = (z == 0) ? Qb : (z == 1) ? Kb : Vb;
    const u16* W = (z == 0) ? Wqb : (z == 1) ? Wkb : Wvb;
    const float* bias = (z == 0) ? bq : (z == 1) ? bk : bv;
    u16* out = (z == 0) ? q_ws : (z == 1) ? k_ws : vt_ws;
    gemm_body<128, 128, false>(A, W, bias, out, (z == 2) ? 1 : 0);
}

__global__ __launch_bounds__(256) void proj_out(
    const u16* __restrict__ A, const u16* __restrict__ Wpb,
    const float* __restrict__ bp, float* __restrict__ y) {
    gemm_body<64, 64, true>(A, Wpb, bp, y, 2);
}

// ---------------------------------------------------------------------------
// attn_fused v5: 4-wave block per (bh, 16-row strip). 1D grid 2048, bijective
// XCD swizzle. E is parked in LDS as UNNORMALIZED bf16 (Pall[wave][s]) right
// after exp; PV runs immediately on unnormalized P (o scaled by rl at the
// end -- softmax is linear in P; v3-validated numerics, but NO recompute).
// This kills the c[4][4] register block (64 VGPR) -> ~70 VGPR total, and LDS
// is 33 KB -> 4 blocks/CU (16 waves/CU vs 12). Epilogue: read Pall, scale by
// rl (LDS-broadcast table), coalesced f32x4 NT a-stores; then fold o*rl into
// the freed Pall space for the cross-wave O reduction.
// ---------------------------------------------------------------------------
__global__ __launch_bounds__(256) void attn_fused(
    const u16* __restrict__ q_ws, const u16* __restrict__ k_ws,
    const u16* __restrict__ vt_ws, float* __restrict__ a_out,
    u16* __restrict__ ao_ws) {
    __shared__ u16 Pall[4][4][1024];  // [wave][s][kseg(8)][m(16)][8] = 32 KB
    __shared__ float Ls[4][16];       // per-wave partial row sums
    __shared__ float Lrl[16];         // broadcast 1/l per row

    const int tid = threadIdx.x;
    const int wave = tid >> 6, lane = tid & 63;
    const int quad = lane >> 4, l16 = lane & 15;

    // bijective XCD swizzle: 2048 blocks, 8 XCDs, 256 per XCD -> 4 bh per XCD.
    const int id = blockIdx.x;
    const int wgid = (id & 7) * 256 + (id >> 3);
    const int bh = wgid >> 6;
    const int strip = 63 - (wgid & 63);   // big strips first within each bh
    const int b = bh >> 4, h = bh & 15;
    const int wrow = strip * 16;
    const int nt = (strip >> 2) + 1;

    const u16* qh = q_ws + (size_t)bh * 65536;
    const u16* kh = k_ws + (size_t)bh * 65536;
    const u16* vh = vt_ws + (size_t)bh * 65536;
    float* ah = a_out + ((size_t)bh << 20);

    bf16x8 qf[2];
    qf[0] = *(const bf16x8*)(qh + (size_t)(wrow + l16) * 64 + quad * 8);
    qf[1] = *(const bf16x8*)(qh + (size_t)(wrow + l16) * 64 + 32 + quad * 8);

    float sum_r[4] = {0.f, 0.f, 0.f, 0.f};
    f32x4 o[4] = {};

    // ---- pass 1: per tile QK^T -> E -> Pall (unnorm bf16) -> PV; row sums ----
    for (int s = 0; s < 4; ++s) {
        const int ct = wave + s * 4;
        if (ct < nt) {
            f32x4 c[4] = {};
#pragma unroll
            for (int ks = 0; ks < 2; ++ks)
#pragma unroll
                for (int cb = 0; cb < 4; ++cb) {
                    bf16x8 kf = *(const bf16x8*)(kh + (size_t)(ct * 64 + cb * 16 + l16) * 64 + ks * 32 + quad * 8);
                    c[cb] = MFMA16(qf[ks], kf, c[cb]);
                }
#pragma unroll
            for (int cb = 0; cb < 4; ++cb) {
                const int s_col = cb * 16 + l16;
                const int col = ct * 64 + s_col;
#pragma unroll
                for (int r = 0; r < 4; ++r) {
                    const int m = quad * 4 + r;
                    const int trow = wrow + m;
                    float E = __expf(c[cb][r] * 0.125f - 20.0f);
                    if (col > trow) E = 0.0f;
                    sum_r[r] += E;
                    Pall[wave][s][(s_col >> 3) * 128 + m * 8 + (s_col & 7)] = f2bf(E);
                }
            }
#pragma unroll
            for (int ks = 0; ks < 2; ++ks) {
                bf16x8 pf = *(const bf16x8*)(&Pall[wave][s][(ks * 4 + quad) * 128 + l16 * 8]);
#pragma unroll
                for (int nb = 0; nb < 4; ++nb) {
                    bf16x8 vf = *(const bf16x8*)(vh + (size_t)(nb * 16 + l16) * 1024 + ct * 64 + ks * 32 + quad * 8);
                    o[nb] = MFMA16(pf, vf, o[nb]);
                }
            }
        }
    }

    // zero the fully-masked upper tiles (nontemporal, vectorized)
    {
        const f32x4 zz = {0.f, 0.f, 0.f, 0.f};
        for (int ct = nt + wave; ct < 16; ct += 4) {
#pragma unroll
            for (int j = 0; j < 4; ++j)
                __builtin_nontemporal_store(
                    zz, (f32x4*)(ah + (size_t)(wrow + j * 4 + quad) * 1024 + ct * 64 + l16 * 4));
        }
    }

    // reduce sums over the 16 column-lanes, then across waves via LDS
#pragma unroll
    for (int r = 0; r < 4; ++r) {
#pragma unroll
        for (int off = 1; off < 16; off <<= 1)
            sum_r[r] += __shfl_xor(sum_r[r], off);
    }
    if (l16 == 0) {
#pragma unroll
        for (int r = 0; r < 4; ++r) Ls[wave][quad * 4 + r] = sum_r[r];
    }
    __syncthreads();

    float rl[4];
#pragma unroll
    for (int r = 0; r < 4; ++r) {
        const int m = quad * 4 + r;
        rl[r] = 1.0f / (Ls[0][m] + Ls[1][m] + Ls[2][m] + Ls[3][m]);
    }
    if (wave == 0 && l16 == 0) {
#pragma unroll
        for (int r = 0; r < 4; ++r) Lrl[quad * 4 + r] = rl[r];
    }
    __syncthreads();

    // ---- epilogue-a: read own Pall, scale by rl, coalesced f32x4 NT stores ----
    {
        const int col4 = l16 * 4;                 // 0..60
        const int kseg = col4 >> 3, koff = col4 & 7;
        for (int s = 0; s < 4; ++s) {
            const int ct = wave + s * 4;
            if (ct < nt) {
#pragma unroll
                for (int i = 0; i < 4; ++i) {
                    const int row = quad + i * 4;  // quad selects base row -> contiguous stores
                    const u16x4 pv = *(const u16x4*)(&Pall[wave][s][kseg * 128 + row * 8 + koff]);
                    const float rlr = Lrl[row];
                    f32x4 vv;
                    vv[0] = bf2f(pv[0]) * rlr;
                    vv[1] = bf2f(pv[1]) * rlr;
                    vv[2] = bf2f(pv[2]) * rlr;
                    vv[3] = bf2f(pv[3]) * rlr;
                    __builtin_nontemporal_store(
                        vv, (f32x4*)(ah + (size_t)(wrow + row) * 1024 + ct * 64 + col4));
                }
            }
        }
    }

    // ---- fold o*rl into own (now free) Pall slice, cross-wave reduce ----
    float* Osum_w = (float*)&Pall[wave][0][0];    // wave-private 4 KB within own 8 KB slice
#pragma unroll
    for (int nb = 0; nb < 4; ++nb)
#pragma unroll
        for (int r = 0; r < 4; ++r) {
            const int row = quad * 4 + r;
            const int d = nb * 16 + l16;
            Osum_w[row * 64 + (d ^ ((row >> 2) << 4))] = o[nb][r] * rl[r];
        }
    __syncthreads();

#pragma unroll
    for (int i = 0; i < 4; ++i) {
        const int e = tid + i * 256;
        const int row = e >> 6, d = e & 63;
        const int sd = row * 64 + (d ^ ((row >> 2) << 4));
        float v = 0.f;
#pragma unroll
        for (int w = 0; w < 4; ++w)
            v += ((const float*)&Pall[w][0][0])[sd];
        ao_ws[((size_t)(b * 1024 + wrow + row)) * 1024 + h * 64 + d] = f2bf(v);
    }
}

// ---------------------------------------------------------------------------
extern "C" void kernel_launch(void* const* d_in, const int* in_sizes, int n_in,
                              void* d_out, int out_size, void* d_ws, size_t ws_size,
                              hipStream_t stream) {
    const float* Q  = (const float*)d_in[0];
    const float* K  = (const float*)d_in[1];
    const float* V  = (const float*)d_in[2];
    const float* Wq = (const float*)d_in[3];
    const float* bq = (const float*)d_in[4];
    const float* Wk = (const float*)d_in[5];
    const float* bk = (const float*)d_in[6];
    const float* Wv = (const float*)d_in[7];
    const float* bv = (const float*)d_in[8];
    const float* Wp = (const float*)d_in[9];
    const float* bp = (const float*)d_in[10];
    // d_in[11] = attn_mask (static causal) -- unused

    float* y = (float*)d_out;                    // [B,T,C] fp32
    float* a = y + (size_t)2 * 1024 * 1024;      // [B,H,T,T] fp32

    const size_t M1 = (size_t)1 << 20;
    u16* q_ws  = (u16*)d_ws;
    u16* k_ws  = q_ws  + 2 * M1;
    u16* vt_ws = k_ws  + 2 * M1;
    u16* ao_ws = vt_ws + 2 * M1;
    u16* Qb    = ao_ws + 2 * M1;
    u16* Kb    = Qb    + 2 * M1;
    u16* Vb    = Kb    + 2 * M1;
    u16* Wqb   = Vb    + 2 * M1;
    u16* Wkb   = Wqb   + M1;
    u16* Wvb   = Wkb   + M1;
    u16* Wpb   = Wvb   + M1;

    hipLaunchKernelGGL(cvt_bf16, dim3(1024, 7), dim3(256), 0, stream,
                       Q, K, V, Wq, Wk, Wv, Wp, Qb, Kb, Vb, Wqb, Wkb, Wvb, Wpb);
    hipLaunchKernelGGL(proj_qkv, dim3(8, 16, 3), dim3(256), 0, stream,
                       Qb, Kb, Vb, Wqb, Wkb, Wvb, bq, bk, bv, q_ws, k_ws, vt_ws);
    hipLaunchKernelGGL(attn_fused, dim3(2048), dim3(256), 0, stream,
                       q_ws, k_ws, vt_ws, a, ao_ws);
    hipLaunchKernelGGL(proj_out, dim3(16, 32, 1), dim3(256), 0, stream,
                       ao_ws, Wpb, bp, y);
}

// Round 8
// 261.817 us; speedup vs baseline: 1.0106x; 1.0106x over previous
//
#include <hip/hip_runtime.h>
#include <hip/hip_bf16.h>

typedef short bf16x8 __attribute__((ext_vector_type(8)));
typedef float f32x4 __attribute__((ext_vector_type(4)));
typedef unsigned short u16;
typedef u16 u16x4 __attribute__((ext_vector_type(4)));
typedef u16 u16x8 __attribute__((ext_vector_type(8)));

#define MFMA16(a, b, c) __builtin_amdgcn_mfma_f32_16x16x32_bf16(a, b, c, 0, 0, 0)

// B=2, T=1024, C=1024, H=16, HD=64.
// Inputs fp32; outputs fp32: y [2M], a [32M].
// d_ws (u16 elems): q[2M] k[2M] vt[2M] ao[2M] Qb[2M] Kb[2M] Vb[2M]
//                   Wqb[1M] Wkb[1M] Wvb[1M] Wpb[1M]  = 18M u16 = 36 MB.

__device__ __forceinline__ u16 f2bf(float f) {
    unsigned u = __builtin_bit_cast(unsigned, f);
    unsigned r = (u + 0x7FFFu + ((u >> 16) & 1u)) >> 16;
    return (u16)r;
}

// ---------------------------------------------------------------------------
// cvt_bf16 prepass: fp32 -> bf16 (RNE) for all GEMM operands, once.
// grid (1024, 7); z: 0=Q 1=K 2=V 3=Wq 4=Wk 5=Wv 6=Wp.
// ---------------------------------------------------------------------------
__global__ __launch_bounds__(256) void cvt_bf16(
    const float* __restrict__ Q, const float* __restrict__ K, const float* __restrict__ V,
    const float* __restrict__ Wq, const float* __restrict__ Wk, const float* __restrict__ Wv,
    const float* __restrict__ Wp,
    u16* __restrict__ Qb, u16* __restrict__ Kb, u16* __restrict__ Vb,
    u16* __restrict__ Wqb, u16* __restrict__ Wkb, u16* __restrict__ Wvb,
    u16* __restrict__ Wpb) {
    const int z = blockIdx.y;
    const float* src;
    u16* dst;
    int n;
    switch (z) {
        case 0: src = Q;  dst = Qb;  n = 1 << 21; break;
        case 1: src = K;  dst = Kb;  n = 1 << 21; break;
        case 2: src = V;  dst = Vb;  n = 1 << 21; break;
        case 3: src = Wq; dst = Wqb; n = 1 << 20; break;
        case 4: src = Wk; dst = Wkb; n = 1 << 20; break;
        case 5: src = Wv; dst = Wvb; n = 1 << 20; break;
        default: src = Wp; dst = Wpb; n = 1 << 20; break;
    }
    const int i = (blockIdx.x * 256 + threadIdx.x) * 8;
    if (i >= n) return;
    float4 f0 = *(const float4*)(src + i);
    float4 f1 = *(const float4*)(src + i + 4);
    u16x8 t;
    t[0] = f2bf(f0.x); t[1] = f2bf(f0.y); t[2] = f2bf(f0.z); t[3] = f2bf(f0.w);
    t[4] = f2bf(f1.x); t[5] = f2bf(f1.y); t[6] = f2bf(f1.z); t[7] = f2bf(f1.w);
    *(u16x8*)(dst + i) = t;
}

// ---------------------------------------------------------------------------
// m97-style bt-GEMM: out = A(Mx1024) @ W(1024x1024)^T + bias.
// Linear LDS [row][64], staged via global_load_lds width=16 (no VALU staging).
// BM x BN tile, BK=64, 4 waves (2x2). proj_qkv: 128x64; proj_out: 64x64.
// mode 0: [b,h,t,d]; mode 1: [b,h,d,t]; mode 2: row-major (fp32 y).
// ---------------------------------------------------------------------------
template <int BM, int BN, bool OF32>
__device__ inline void gemm_body(const u16* __restrict__ A,
                                 const u16* __restrict__ W,
                                 const float* __restrict__ bias,
                                 void* __restrict__ outp, int mode) {
    __shared__ u16 As[BM * 64];   // [row][64] linear
    __shared__ u16 Bs[BN * 64];   // [row][64] linear

    const int tid = threadIdx.x;
    const int wave = tid >> 6, lane = tid & 63;
    const int quad = lane >> 4, l16 = lane & 15;
    constexpr int WM = BM / 2;    // wave tile rows
    constexpr int WN = BN / 2;    // wave tile cols
    constexpr int MI = WM / 16;   // m-frags per wave
    constexpr int NI = WN / 16;   // n-frags per wave
    const int wm = (wave >> 1) * WM;
    const int wn = (wave & 1) * WN;
    const int m0 = blockIdx.y * BM;
    const int n0 = blockIdx.x * BN;

    f32x4 acc[MI][NI] = {};

    const int lrow = lane >> 3;
    const int lseg = lane & 7;
    const u16* Ag = A + (size_t)(m0 + wave * 8 + lrow) * 1024 + lseg * 8;
    const u16* Wg = W + (size_t)(n0 + wave * 8 + lrow) * 1024 + lseg * 8;
    u16* AsBase = As + wave * 8 * 64;
    u16* BsBase = Bs + wave * 8 * 64;

    for (int kt = 0; kt < 16; ++kt) {
        const int k0 = kt * 64;
        __syncthreads();
#pragma unroll
        for (int rr = 0; rr < BM / 32; ++rr)
            __builtin_amdgcn_global_load_lds(
                (const __attribute__((address_space(1))) void*)(Ag + (size_t)rr * 32 * 1024 + k0),
                (__attribute__((address_space(3))) void*)(AsBase + rr * 32 * 64), 16, 0, 0);
#pragma unroll
        for (int rr = 0; rr < BN / 32; ++rr)
            __builtin_amdgcn_global_load_lds(
                (const __attribute__((address_space(1))) void*)(Wg + (size_t)rr * 32 * 1024 + k0),
                (__attribute__((address_space(3))) void*)(BsBase + rr * 32 * 64), 16, 0, 0);
        __syncthreads();
#pragma unroll
        for (int ks = 0; ks < 2; ++ks) {
            bf16x8 af[MI], bfr[NI];
#pragma unroll
            for (int mi = 0; mi < MI; ++mi)
                af[mi] = *(const bf16x8*)(As + (wm + mi * 16 + l16) * 64 + ks * 32 + quad * 8);
#pragma unroll
            for (int ni = 0; ni < NI; ++ni)
                bfr[ni] = *(const bf16x8*)(Bs + (wn + ni * 16 + l16) * 64 + ks * 32 + quad * 8);
#pragma unroll
            for (int mi = 0; mi < MI; ++mi)
#pragma unroll
                for (int ni = 0; ni < NI; ++ni)
                    acc[mi][ni] = MFMA16(af[mi], bfr[ni], acc[mi][ni]);
        }
    }

#pragma unroll
    for (int ni = 0; ni < NI; ++ni) {
        const int n = n0 + wn + ni * 16 + l16;
        const float bv = bias[n];
#pragma unroll
        for (int mi = 0; mi < MI; ++mi) {
#pragma unroll
            for (int r = 0; r < 4; ++r) {
                const int m = m0 + wm + mi * 16 + quad * 4 + r;
                const float val = acc[mi][ni][r] + bv;
                size_t idx;
                if (mode == 0) {
                    int b = m >> 10, t = m & 1023, h = n >> 6, d = n & 63;
                    idx = ((size_t)((b * 16 + h) * 1024 + t)) * 64 + d;
                } else if (mode == 1) {
                    int b = m >> 10, t = m & 1023, h = n >> 6, d = n & 63;
                    idx = ((size_t)((b * 16 + h) * 64 + d)) * 1024 + t;
                } else {
                    idx = (size_t)m * 1024 + n;
                }
                if (OF32) ((float*)outp)[idx] = val;
                else      ((u16*)outp)[idx] = f2bf(val);
            }
        }
    }
}

__global__ __launch_bounds__(256) void proj_qkv(
    const u16* __restrict__ Qb, const u16* __restrict__ Kb, const u16* __restrict__ Vb,
    const u16* __restrict__ Wqb, const u16* __restrict__ Wkb, const u16* __restrict__ Wvb,
    const float* __restrict__ bq, const float* __restrict__ bk, const float* __restrict__ bv,
    u16* __restrict__ q_ws, u16* __restrict__ k_ws, u16* __restrict__ vt_ws) {
    const int z = blockIdx.z;
    const u16* A = (z == 0) ? Qb : (z == 1) ? Kb : Vb;
    const u16* W = (z == 0) ? Wqb : (z == 1) ? Wkb : Wvb;
    const float* bias = (z == 0) ? bq : (z == 1) ? bk : bv;
    u16* out = (z == 0) ? q_ws : (z == 1) ? k_ws : vt_ws;
    gemm_body<128, 64, false>(A, W, bias, out, (z == 2) ? 1 : 0);
}

__global__ __launch_bounds__(256) void proj_out(
    const u16* __restrict__ A, const u16* __restrict__ Wpb,
    const float* __restrict__ bp, float* __restrict__ y) {
    gemm_body<64, 64, true>(A, Wpb, bp, y, 2);
}

// ---------------------------------------------------------------------------
// attn_fused v6: v4 structure + SWAPPED QK^T (mfma(K,Q)): lane owns ONE q-row
// (l16) with 4 consecutive k per fragment. Wins: single row-sum accumulator +
// 2 shuffles (was 16); P written as 4x ds_write_b64/tile (was 16 scalar),
// XOR-swizzled conflict-free; a-stores go DIRECTLY from registers as f32x4 NT
// (scratch transpose deleted). PV / O-fold / zero-fill / XCD swizzle as v4.
// ---------------------------------------------------------------------------
__global__ __launch_bounds__(256) void attn_fused(
    const u16* __restrict__ q_ws, const u16* __restrict__ k_ws,
    const u16* __restrict__ vt_ws, float* __restrict__ a_out,
    u16* __restrict__ ao_ws) {
    __shared__ u16 P[4][1024];        // per-wave [qrow 16][k 64] linear, XOR-swizzled
    __shared__ float Ls[4][16];       // per-wave row sums
    __shared__ float Lrl[16];         // 1/l per row
    __shared__ float Osum[4][1024];   // per-wave partial O, xor-swizzled

    const int tid = threadIdx.x;
    const int wave = tid >> 6, lane = tid & 63;
    const int quad = lane >> 4, l16 = lane & 15;

    // bijective XCD swizzle: 2048 blocks, 8 XCDs, 256 per XCD -> 4 bh per XCD.
    const int id = blockIdx.x;
    const int wgid = (id & 7) * 256 + (id >> 3);
    const int bh = wgid >> 6;
    const int strip = 63 - (wgid & 63);   // big strips first within each bh
    const int b = bh >> 4, h = bh & 15;
    const int wrow = strip * 16;
    const int nt = (strip >> 2) + 1;

    const u16* qh = q_ws + (size_t)bh * 65536;
    const u16* kh = k_ws + (size_t)bh * 65536;
    const u16* vh = vt_ws + (size_t)bh * 65536;
    float* ah = a_out + ((size_t)bh << 20);

    bf16x8 qf[2];
    qf[0] = *(const bf16x8*)(qh + (size_t)(wrow + l16) * 64 + quad * 8);
    qf[1] = *(const bf16x8*)(qh + (size_t)(wrow + l16) * 64 + 32 + quad * 8);

    const int qrow = wrow + l16;          // this lane's q-row (global)
    const int swz = (l16 & 7) << 4;       // LDS XOR swizzle for P

    // ---- pass 1: swapped QK^T -> E in regs (c[s][cb][r] = E[q=l16][k]) ----
    f32x4 c[4][4] = {};
    float sum_l = 0.f;

#pragma unroll
    for (int s = 0; s < 4; ++s) {
        const int ct = wave + s * 4;
        if (ct < nt) {
#pragma unroll
            for (int ks = 0; ks < 2; ++ks)
#pragma unroll
                for (int cb = 0; cb < 4; ++cb) {
                    bf16x8 kf = *(const bf16x8*)(kh + (size_t)(ct * 64 + cb * 16 + l16) * 64 + ks * 32 + quad * 8);
                    c[s][cb] = MFMA16(kf, qf[ks], c[s][cb]);   // SWAPPED: row=k, col=q
                }
#pragma unroll
            for (int cb = 0; cb < 4; ++cb) {
#pragma unroll
                for (int r = 0; r < 4; ++r) {
                    const int kg = ct * 64 + cb * 16 + quad * 4 + r;
                    float E = __expf(c[s][cb][r] * 0.125f - 20.0f);
                    if (kg > qrow) E = 0.0f;
                    c[s][cb][r] = E;
                    sum_l += E;
                }
            }
        }
    }

    // zero the fully-masked upper tiles (nontemporal, vectorized)
    {
        const f32x4 zz = {0.f, 0.f, 0.f, 0.f};
        for (int ct = nt + wave; ct < 16; ct += 4) {
#pragma unroll
            for (int j = 0; j < 4; ++j)
                __builtin_nontemporal_store(
                    zz, (f32x4*)(ah + (size_t)(wrow + j * 4 + quad) * 1024 + ct * 64 + l16 * 4));
        }
    }

    // row-sum: reduce across quads (2 shuffles), then across waves via LDS
    sum_l += __shfl_xor(sum_l, 16);
    sum_l += __shfl_xor(sum_l, 32);
    if (lane < 16) Ls[wave][lane] = sum_l;
    __syncthreads();
    if (wave == 0 && lane < 16)
        Lrl[lane] = 1.0f / (Ls[0][lane] + Ls[1][lane] + Ls[2][lane] + Ls[3][lane]);
    __syncthreads();

    const float rl_me = Lrl[l16];

    // ---- pass 2: normalize -> direct f32x4 NT a-store + packed P -> PV ----
    u16* Pw = &P[wave][0];
    f32x4 o[4] = {};
#pragma unroll
    for (int s = 0; s < 4; ++s) {
        const int ct = wave + s * 4;
        if (ct < nt) {
#pragma unroll
            for (int cb = 0; cb < 4; ++cb) {
                f32x4 vv;
                u16x4 pk;
#pragma unroll
                for (int r = 0; r < 4; ++r) {
                    const float v = c[s][cb][r] * rl_me;
                    vv[r] = v;
                    pk[r] = f2bf(v);
                }
                __builtin_nontemporal_store(
                    vv, (f32x4*)(ah + (size_t)qrow * 1024 + ct * 64 + cb * 16 + quad * 4));
                *(u16x4*)((char*)Pw + ((l16 * 128 + cb * 32 + quad * 8) ^ swz)) = pk;
            }
#pragma unroll
            for (int ks = 0; ks < 2; ++ks) {
                bf16x8 pf = *(const bf16x8*)((const char*)Pw + ((l16 * 128 + (ks * 4 + quad) * 16) ^ swz));
#pragma unroll
                for (int nb = 0; nb < 4; ++nb) {
                    bf16x8 vf = *(const bf16x8*)(vh + (size_t)(nb * 16 + l16) * 1024 + ct * 64 + ks * 32 + quad * 8);
                    o[nb] = MFMA16(pf, vf, o[nb]);
                }
            }
        }
    }

    // ---- fold o (normalized) into Osum, cross-wave reduce, write ao ----
#pragma unroll
    for (int nb = 0; nb < 4; ++nb)
#pragma unroll
        for (int r = 0; r < 4; ++r) {
            const int row = quad * 4 + r;
            const int d = nb * 16 + l16;
            Osum[wave][row * 64 + (d ^ ((row >> 2) << 4))] = o[nb][r];
        }
    __syncthreads();

#pragma unroll
    for (int i = 0; i < 4; ++i) {
        const int e = tid + i * 256;
        const int row = e >> 6, d = e & 63;
        const int sd = row * 64 + (d ^ ((row >> 2) << 4));
        const float v = Osum[0][sd] + Osum[1][sd] + Osum[2][sd] + Osum[3][sd];
        ao_ws[((size_t)(b * 1024 + wrow + row)) * 1024 + h * 64 + d] = f2bf(v);
    }
}

// ---------------------------------------------------------------------------
extern "C" void kernel_launch(void* const* d_in, const int* in_sizes, int n_in,
                              void* d_out, int out_size, void* d_ws, size_t ws_size,
                              hipStream_t stream) {
    const float* Q  = (const float*)d_in[0];
    const float* K  = (const float*)d_in[1];
    const float* V  = (const float*)d_in[2];
    const float* Wq = (const float*)d_in[3];
    const float* bq = (const float*)d_in[4];
    const float* Wk = (const float*)d_in[5];
    const float* bk = (const float*)d_in[6];
    const float* Wv = (const float*)d_in[7];
    const float* bv = (const float*)d_in[8];
    const float* Wp = (const float*)d_in[9];
    const float* bp = (const float*)d_in[10];
    // d_in[11] = attn_mask (static causal) -- unused

    float* y = (float*)d_out;                    // [B,T,C] fp32
    float* a = y + (size_t)2 * 1024 * 1024;      // [B,H,T,T] fp32

    const size_t M1 = (size_t)1 << 20;
    u16* q_ws  = (u16*)d_ws;
    u16* k_ws  = q_ws  + 2 * M1;
    u16* vt_ws = k_ws  + 2 * M1;
    u16* ao_ws = vt_ws + 2 * M1;
    u16* Qb    = ao_ws + 2 * M1;
    u16* Kb    = Qb    + 2 * M1;
    u16* Vb    = Kb    + 2 * M1;
    u16* Wqb   = Vb    + 2 * M1;
    u16* Wkb   = Wqb   + M1;
    u16* Wvb   = Wkb   + M1;
    u16* Wpb   = Wvb   + M1;

    hipLaunchKernelGGL(cvt_bf16, dim3(1024, 7), dim3(256), 0, stream,
                       Q, K, V, Wq, Wk, Wv, Wp, Qb, Kb, Vb, Wqb, Wkb, Wvb, Wpb);
    hipLaunchKernelGGL(proj_qkv, dim3(16, 16, 3), dim3(256), 0, stream,
                       Qb, Kb, Vb, Wqb, Wkb, Wvb, bq, bk, bv, q_ws, k_ws, vt_ws);
    hipLaunchKernelGGL(attn_fused, dim3(2048), dim3(256), 0, stream,
                       q_ws, k_ws, vt_ws, a, ao_ws);
    hipLaunchKernelGGL(proj_out, dim3(16, 32, 1), dim3(256), 0, stream,
                       ao_ws, Wpb, bp, y);
}